// Round 9
// baseline (599.412 us; speedup 1.0000x reference)
//
#include <hip/hip_runtime.h>
#include <hip/hip_fp16.h>

#define RCUT 3.5f
#define TTAB 2048

static __device__ __forceinline__ float sigmoidf_(float x) { return 1.0f / (1.0f + expf(-x)); }
static __device__ __forceinline__ float siluf(float x) { return x / (1.0f + expf(-x)); }
// nan_to_num: 0 for NaN/Inf (bit-pattern test, fast-math immune)
static __device__ __forceinline__ float san(float x) {
    return ((__float_as_uint(x) & 0x7F800000u) != 0x7F800000u) ? x : 0.f;
}
// fp16 pack/unpack for the layer-invariant edge records
static __device__ __forceinline__ unsigned pk(float a, float b) {
    __half2 h = __floats2half2_rn(a, b);
    return *reinterpret_cast<unsigned*>(&h);
}
static __device__ __forceinline__ float2 upk(unsigned u) {
    __half2 h = *reinterpret_cast<__half2*>(&u);
    return __half22float2(h);
}

// ---------------- fused: radial table (blocks 0..TTAB) + degree count/slot (rest) ------------
// k_count's atomicAdd RETURN VALUE is the edge's local slot -> stored coalesced by edge id.
__global__ __launch_bounds__(256) void k_tabcount(const float* means, const float* betas,
                        const float* rad_w1, const float* rad_b1,
                        const float* rad_w2, const float* rad_b2,
                        const float* ne_dw, const float* ne_db,
                        float* tab,
                        const int* ei, int* cnt_dst, int* cnt_src,
                        int* loc_dst, int* loc_src, int E) {
    if (blockIdx.x >= TTAB) {
        int e = (blockIdx.x - TTAB) * 256 + threadIdx.x;
        if (e < E) {
            loc_dst[e] = atomicAdd(cnt_dst + ei[E + e], 1);
            loc_src[e] = atomicAdd(cnt_src + ei[e], 1);
        }
        return;
    }
    __shared__ float red[3][4];
    int i = blockIdx.x;
    int h = threadIdx.x;
    int lane = h & 63, wv = h >> 6;
    float d  = (float)i * (RCUT / (float)(TTAB - 1));
    float dc = fmaxf(d, 1e-6f);
    float C  = (dc < RCUT) ? 0.5f * (cosf(dc * (3.14159265358979f / RCUT)) + 1.0f) : 0.0f;
    float ex = expf(-(5.0f / RCUT) * dc);
    float rbf[8];
#pragma unroll
    for (int nn = 0; nn < 8; ++nn) {
        float b = fmaxf(betas[nn], 1e-6f);
        float t = ex - means[nn];
        rbf[nn] = C * expf(-b * t * t);
    }
    float con[3];
#pragma unroll
    for (int l = 0; l < 3; ++l) {
        float cc = rad_b1[l * 256 + h];
#pragma unroll
        for (int nn = 0; nn < 8; ++nn) cc += rbf[nn] * rad_w1[(l * 8 + nn) * 256 + h];
        con[l] = siluf(cc) * rad_w2[l * 256 + h];
    }
#pragma unroll
    for (int m = 1; m < 64; m <<= 1) {
        con[0] += __shfl_xor(con[0], m, 64);
        con[1] += __shfl_xor(con[1], m, 64);
        con[2] += __shfl_xor(con[2], m, 64);
    }
    if (lane == 0) { red[0][wv] = con[0]; red[1][wv] = con[1]; red[2][wv] = con[2]; }
    __syncthreads();
    if (h < 3)
        tab[i * 40 + h] = rad_b2[h] + red[h][0] + red[h][1] + red[h][2] + red[h][3];
    else if (h == 3)
        tab[i * 40 + 3] = 0.f;
    else if (h < 36) {
        int c = h - 4;
        float wvv = ne_db[c];
#pragma unroll
        for (int nn = 0; nn < 8; ++nn) wvv += rbf[nn] * ne_dw[nn * 32 + c];
        tab[i * 40 + h] = wvv * C;   // W includes cutoff_fn(d)
    } else if (h < 40)
        tab[i * 40 + h] = 0.f;
}

// ---------------- dual exclusive scan: per-thread chunk + single block scan ------------------
__global__ __launch_bounds__(1024) void k_scan2(const int* cntA, int* rowA,
                        const int* cntB, int* rowB, int n) {
    __shared__ int wsum[16];
    const int* cnt = blockIdx.x ? cntB : cntA;
    int* rowptr    = blockIdx.x ? rowB : rowA;
    int tid = threadIdx.x, lane = tid & 63, wv = tid >> 6;
    int per = (n + 1023) >> 10;
    int beg = tid * per; if (beg > n) beg = n;
    int end = beg + per; if (end > n) end = n;
    int s = 0;
    for (int i = beg; i < end; ++i) s += cnt[i];
    int v = s;
#pragma unroll
    for (int m = 1; m < 64; m <<= 1) {
        int t = __shfl_up(v, m, 64);
        if (lane >= m) v += t;
    }
    if (lane == 63) wsum[wv] = v;
    __syncthreads();
    int wbase = 0;
    for (int j = 0; j < wv; ++j) wbase += wsum[j];
    int run = wbase + v - s;               // exclusive prefix for this thread's chunk
    for (int i = beg; i < end; ++i) {
        int val = cnt[i];
        rowptr[i] = run;
        run += val;
    }
    if (tid == 1023) rowptr[n] = run;
}

// ---------------- edge-compute + scatter, NO atomics (slots precomputed) ---------------------
// recH (2x uint4 = 32 B/edge):
//   [0]: pk(ae0,e1x) pk(e1y,e1z) col pk(q12,q22)    <- wave0's half
//   [1]: pk(q00,q01) pk(q02,q11) col 0              <- wave1's half (col duplicated!)
// slot = row[node] + loc[e]; all gathers are L2-resident (pos 240KB, row 80KB, tab 320KB).
__global__ void k_edge_fill(const float* pos, const float* alpha,
                            const int* ei, const float* tab, const int* z,
                            const int* row_dst, const int* row_src,
                            const int* loc_dst, const int* loc_src,
                            uint4* recH, int2* rec_src, int E) {
    int e = blockIdx.x * blockDim.x + threadIdx.x;
    if (e >= E) return;
    int sn = ei[e], dn = ei[E + e];
    float rx = pos[dn * 3]     - pos[sn * 3];
    float ry = pos[dn * 3 + 1] - pos[sn * 3 + 1];
    float rz = pos[dn * 3 + 2] - pos[sn * 3 + 2];
    float d = sqrtf(rx * rx + ry * ry + rz * rz + 1e-12f);
    float inv = 1.0f / d;
    rx *= inv; ry *= inv; rz *= inv;
    float u = fminf(d, RCUT) * ((float)(TTAB - 1) / RCUT);
    int i0 = (int)u; if (i0 > TTAB - 2) i0 = TTAB - 2;
    float f = u - (float)i0;
    const float* t0 = tab + i0 * 40;
    float c0 = t0[0] + f * (t0[40] - t0[0]);
    float c1 = t0[1] + f * (t0[41] - t0[1]);
    float c2 = t0[2] + f * (t0[42] - t0[2]);
    float al = alpha[e];
    float ae0 = san(al * c0);
    float k1 = 1.73205081f * al * c1;      // sqrt(3)*alpha*coeff1
    float k2 = al * c2;
    float e20 = san(5.47722558f * rx * ry * k2);                             // sqrt(30) xy
    float e21 = san(5.47722558f * ry * rz * k2);
    float e22 = san(1.58113883f * (2.f * rz * rz - rx * rx - ry * ry) * k2); // sqrt(2.5)
    float e23 = san(5.47722558f * rx * rz * k2);
    float e24 = san(2.73861279f * (rx * rx - ry * ry) * k2);                 // sqrt(7.5)
    const float S2 = 0.70710678f, S6 = 0.40824829f;
    float q00 = -S6 * e22 + S2 * e24;
    float q01 = S2 * e20;
    float q02 = S2 * e23;
    float q11 = -S6 * e22 - S2 * e24;
    float q12 = S2 * e21;
    float q22 = 2.f * S6 * e22;
    int p  = row_dst[dn] + loc_dst[e];
    int p2 = row_src[sn] + loc_src[e];
    uint4 r0, r1;
    r0.x = pk(ae0, san(k1 * rx));
    r0.y = pk(san(k1 * ry), san(k1 * rz));
    r0.z = (unsigned)sn;
    r0.w = pk(q12, q22);
    r1.x = pk(q00, q01);
    r1.y = pk(q02, q11);
    r1.z = (unsigned)sn;                   // duplicated col: wave1 stages independently
    r1.w = 0u;
    recH[(size_t)p * 2]     = r0;
    recH[(size_t)p * 2 + 1] = r1;
    float uc = fminf(u, (float)(TTAB - 1) - 1e-3f);
    rec_src[p2] = make_int2(__float_as_int(uc), z[dn]);
}

// ---------------- aggr (src-sorted records) + initial node embed -----------------------------
// wave-synchronous: all LDS is per-wave
__global__ __launch_bounds__(256) void k_aggr(const int* row_src, const int2* recs,
        const int* z, const float* tab, const float* ne_emb, const float* atom_emb,
        const float* ne_cw, const float* ne_cb,
        float* sbuf, float* vbuf, int N) {
    __shared__ float part[4][64];
    __shared__ float cat[4][64];
    int wv = threadIdx.x >> 6, lane = threadIdx.x & 63;
    int n = blockIdx.x * 4 + wv;
    bool act = n < N;
    int g = lane >> 5, li = lane & 31;
    float acc = 0.f;
    if (act) {
        int r0 = row_src[n], r1 = row_src[n + 1];
        int half = (r1 - r0) >> 1;
        int kb = g ? (r0 + half) : r0;
        int ke = g ? r1 : (r0 + half);
        int k = kb;
        for (; k + 2 <= ke; k += 2) {
            int2 rA = recs[k], rB = recs[k + 1];
            float uA = __int_as_float(rA.x), uB = __int_as_float(rB.x);
            int iA = (int)uA, iB = (int)uB;
            float fA = uA - (float)iA, fB = uB - (float)iB;
            float wA0 = tab[iA * 40 + 4 + li], wA1 = tab[iA * 40 + 44 + li];
            float wB0 = tab[iB * 40 + 4 + li], wB1 = tab[iB * 40 + 44 + li];
            float eA = ne_emb[rA.y * 32 + li], eB = ne_emb[rB.y * 32 + li];
            acc += (wA0 + fA * (wA1 - wA0)) * eA + (wB0 + fB * (wB1 - wB0)) * eB;
        }
        for (; k < ke; ++k) {
            int2 r = recs[k];
            float u = __int_as_float(r.x);
            int i0 = (int)u; float f = u - (float)i0;
            float w0 = tab[i0 * 40 + 4 + li], w1 = tab[i0 * 40 + 44 + li];
            acc += (w0 + f * (w1 - w0)) * ne_emb[r.y * 32 + li];
        }
    }
    part[wv][lane] = acc;
    __builtin_amdgcn_wave_barrier();
    if (act && lane < 32) {
        cat[wv][lane] = atom_emb[z[n] * 32 + lane];
        cat[wv][32 + lane] = part[wv][lane] + part[wv][32 + lane];
    }
    __builtin_amdgcn_wave_barrier();
    if (act && lane < 32) {
        float so = ne_cb[lane];
        for (int j = 0; j < 64; ++j) so += cat[wv][j] * ne_cw[j * 32 + lane];
        sbuf[n * 32 + lane] = so;
    }
    if (act && lane < 48) vbuf[n * 48 + lane] = 0.f;
}

// half-block s accumulate (2 edges per lane-half)
#define SBLK2(BIDX, X0, X1)                                                             \
    {                                                                                   \
        int e_ = ((BIDX) << 2) + 2 * h;                                                 \
        float4 A0 = eA[e_], A1 = eA[e_ + 1];                                            \
        a0  += X0 * A0.x + X1 * A1.x;                                                   \
        a1x += X0 * A0.y + X1 * A1.y;                                                   \
        a1y += X0 * A0.z + X1 * A1.z;                                                   \
        a1z += X0 * A0.w + X1 * A1.w;                                                   \
    }

// one-edge v accumulate (edge slot g of block; uses wave1's private staging)
#define VBLK1(BIDX, U, V, W)                                                            \
    {                                                                                   \
        int e_ = ((BIDX) << 2) + g;                                                     \
        float4 Aa = eA2[e_];                                                            \
        float4 Qa = eQ[e_];                                                             \
        float2 Ra = eR2[e_];                                                            \
        adv += U * Aa.y + V * Aa.z + W * Aa.w;                                          \
        a2x += U * Aa.x; a2y += V * Aa.x; a2z += W * Aa.x;                              \
        a3x += Qa.x * U + Qa.y * V + Qa.z * W;                                          \
        a3y += Qa.y * U + Qa.w * V + Ra.x * W;                                          \
        a3z += Qa.z * U + Ra.x * V + Ra.y * W;                                          \
    }

// ---------------- fused layer: 1 node / 128-thread block, fully decoupled waves --------------
// wave0 = s-path, wave1 = v-path. Each wave stages its OWN edge data (col duplicated in both
// record halves) -> no pre-loop __syncthreads; waves are independent until moment-combine.
// Depth-4 gather pipeline (8 s-loads / 12 v-floats in flight) to cover ~500cy L3 latency.
// Round-6 lesson kept: per-MAC column weight loads w[i*32+lane] (wave-coalesced).
__global__ __launch_bounds__(128) void k_layer(const int* __restrict__ row_dst,
        const uint4* __restrict__ recH,
        const float* __restrict__ sOld, const float* __restrict__ vOld,
        const float* w00, const float* w110, const float* w01,
        const float* w10, const float* w12,
        const float* self_ws, const float* self_wv,
        const float* pre_ws, const float* pre_wv,
        const float* post_ws, const float* post_wv,
        const float* ln_g, const float* ln_b,
        const float* g_w1, const float* g_b1,
        const float* g_w2, const float* g_b2,
        float* __restrict__ sNew, float* __restrict__ vNew,
        float* __restrict__ out, int N) {
    __shared__ __align__(16) float4 eA[64];    // wave0: A
    __shared__ __align__(16) int    eC[64];    // wave0: cols
    __shared__ __align__(16) float4 eA2[64];   // wave1: A (private copy)
    __shared__ __align__(16) float4 eQ[64];    // wave1: Q4
    __shared__ __align__(16) float2 eR2[64];   // wave1: {q12,q22}
    __shared__ __align__(16) int    eC2[64];   // wave1: cols (private copy)
    __shared__ float M[240];
    __shared__ float S[32], Vt[48], P[48];
    int wv = threadIdx.x >> 6, lane = threadIdx.x & 63;
    int n = blockIdx.x;
    int r0 = row_dst[n], r1 = row_dst[n + 1];
    int deg = r1 - r0;
    int cap = deg < 64 ? deg : 64;
    int nblk = cap >> 2;

    if (wv == 0) {
        // ================= s-path wave (self-sufficient) =================
        if (lane < cap) {
            uint4 rA = recH[(size_t)(r0 + lane) * 2];
            float2 p0 = upk(rA.x), p1 = upk(rA.y);
            eA[lane] = make_float4(p0.x, p0.y, p1.x, p1.y);
            eC[lane] = (int)rA.z;
        }
        if (lane < 32) S[lane] = sOld[(size_t)n * 32 + lane];
        __builtin_amdgcn_wave_barrier();

        const int4* eC4 = (const int4*)eC;
        int h = lane >> 5, d = lane & 31;
        float a0 = 0.f, a1x = 0.f, a1y = 0.f, a1z = 0.f;
        float xs0[4], xs1[4];
#pragma unroll
        for (int j = 0; j < 4; ++j) {
            if (j < nblk) {
                int4 c4 = eC4[j];
                xs0[j] = sOld[(h ? c4.z : c4.x) * 32 + d];
                xs1[j] = sOld[(h ? c4.w : c4.y) * 32 + d];
            }
        }
        int b = 0;
        for (; b + 4 <= nblk; b += 4) {
            float nx0[4], nx1[4];
#pragma unroll
            for (int j = 0; j < 4; ++j) {
                if (b + 4 + j < nblk) {
                    int4 c4 = eC4[b + 4 + j];
                    nx0[j] = sOld[(h ? c4.z : c4.x) * 32 + d];
                    nx1[j] = sOld[(h ? c4.w : c4.y) * 32 + d];
                }
            }
#pragma unroll
            for (int j = 0; j < 4; ++j) { SBLK2(b + j, xs0[j], xs1[j]); }
#pragma unroll
            for (int j = 0; j < 4; ++j) {
                if (b + 4 + j < nblk) { xs0[j] = nx0[j]; xs1[j] = nx1[j]; }
            }
        }
        int r = nblk - b;
#pragma unroll
        for (int j = 0; j < 4; ++j) { if (j < r) { SBLK2(b + j, xs0[j], xs1[j]); } }
        for (int k = r0 + (nblk << 2); k < r1; ++k) {   // tail (+ deg>64 overflow), half 0 only
            if (h == 0) {
                uint4 rA = recH[(size_t)k * 2];
                float2 p0 = upk(rA.x), p1 = upk(rA.y);
                int cc = (int)rA.z;
                float xx = sOld[cc * 32 + d];
                a0 += xx * p0.x; a1x += xx * p0.y; a1y += xx * p1.x; a1z += xx * p1.y;
            }
        }
        a0  += __shfl_xor(a0, 32, 64);
        a1x += __shfl_xor(a1x, 32, 64);
        a1y += __shfl_xor(a1y, 32, 64);
        a1z += __shfl_xor(a1z, 32, 64);
        if (lane < 32) {
            M[lane] = a0; M[32 + lane] = a1x; M[64 + lane] = a1y; M[96 + lane] = a1z;
        }
    } else {
        // ================= v-path wave (self-sufficient) =================
        if (lane < cap) {
            uint4 rA = recH[(size_t)(r0 + lane) * 2];
            uint4 rB = recH[(size_t)(r0 + lane) * 2 + 1];
            float2 p0 = upk(rA.x), p1 = upk(rA.y), p3 = upk(rA.w);
            float2 q0 = upk(rB.x), q1 = upk(rB.y);
            eA2[lane] = make_float4(p0.x, p0.y, p1.x, p1.y);
            eR2[lane] = make_float2(p3.x, p3.y);
            eQ[lane]  = make_float4(q0.x, q0.y, q1.x, q1.y);
            eC2[lane] = (int)rB.z;
        }
        if (lane < 48) {
            int c_ = lane >> 4, o_ = lane & 15;
            Vt[c_ * 16 + o_] = vOld[(size_t)n * 48 + o_ * 3 + c_];
        }
        __builtin_amdgcn_wave_barrier();

        int g = lane >> 4, m = lane & 15;
        float adv = 0.f, a2x = 0.f, a2y = 0.f, a2z = 0.f, a3x = 0.f, a3y = 0.f, a3z = 0.f;
        float vu[4], vV[4], vw[4];
#pragma unroll
        for (int j = 0; j < 4; ++j) {
            if (j < nblk) {
                const float* vp = vOld + (size_t)eC2[(j << 2) + g] * 48 + m * 3;
                vu[j] = vp[0]; vV[j] = vp[1]; vw[j] = vp[2];
            }
        }
        int b = 0;
        for (; b + 4 <= nblk; b += 4) {
            float nu[4], nv[4], nw[4];
#pragma unroll
            for (int j = 0; j < 4; ++j) {
                if (b + 4 + j < nblk) {
                    const float* vp = vOld + (size_t)eC2[((b + 4 + j) << 2) + g] * 48 + m * 3;
                    nu[j] = vp[0]; nv[j] = vp[1]; nw[j] = vp[2];
                }
            }
#pragma unroll
            for (int j = 0; j < 4; ++j) { VBLK1(b + j, vu[j], vV[j], vw[j]); }
#pragma unroll
            for (int j = 0; j < 4; ++j) {
                if (b + 4 + j < nblk) { vu[j] = nu[j]; vV[j] = nv[j]; vw[j] = nw[j]; }
            }
        }
        int r = nblk - b;
#pragma unroll
        for (int j = 0; j < 4; ++j) { if (j < r) { VBLK1(b + j, vu[j], vV[j], vw[j]); } }
        for (int k = r0 + (nblk << 2); k < r1; ++k) {   // tail, slot group 0 only
            if (g == 0) {
                uint4 rA = recH[(size_t)k * 2];
                uint4 rB = recH[(size_t)k * 2 + 1];
                float2 p0 = upk(rA.x), p1 = upk(rA.y), p3 = upk(rA.w);
                float2 q0 = upk(rB.x), q1 = upk(rB.y);
                int cc = (int)rA.z;
                const float* vp = vOld + (size_t)cc * 48 + m * 3;
                float vx = vp[0], vy = vp[1], vz = vp[2];
                adv += vx * p0.y + vy * p1.x + vz * p1.y;
                a2x += vx * p0.x; a2y += vy * p0.x; a2z += vz * p0.x;
                a3x += q0.x * vx + q0.y * vy + q1.x * vz;
                a3y += q0.y * vx + q1.y * vy + p3.x * vz;
                a3z += q1.x * vx + p3.x * vy + p3.y * vz;
            }
        }
        adv += __shfl_xor(adv, 16, 64); adv += __shfl_xor(adv, 32, 64);
        a2x += __shfl_xor(a2x, 16, 64); a2x += __shfl_xor(a2x, 32, 64);
        a2y += __shfl_xor(a2y, 16, 64); a2y += __shfl_xor(a2y, 32, 64);
        a2z += __shfl_xor(a2z, 16, 64); a2z += __shfl_xor(a2z, 32, 64);
        a3x += __shfl_xor(a3x, 16, 64); a3x += __shfl_xor(a3x, 32, 64);
        a3y += __shfl_xor(a3y, 16, 64); a3y += __shfl_xor(a3y, 32, 64);
        a3z += __shfl_xor(a3z, 16, 64); a3z += __shfl_xor(a3z, 32, 64);
        if (lane < 16) {
            M[128 + m] = adv;
            M[144 + m] = a2x; M[160 + m] = a2y; M[176 + m] = a2z;
            M[192 + m] = a3x; M[208 + m] = a3y; M[224 + m] = a3z;
        }
    }
    __syncthreads();                                   // #2: moments complete

    // ================= node update, split across the two waves =================
    float sln = 0.f, pv = 0.f;
    int c = lane >> 4, o = lane & 15;
    if (wv == 0) {
        // --- s-chain ---
        float s1 = 0.f;
        if (lane < 32) {
            for (int i = 0; i < 32; ++i) s1 += M[i] * w00[i * 32 + lane];
            for (int v = 0; v < 16; ++v) s1 += M[128 + v] * w110[v * 32 + lane];
            for (int i = 0; i < 32; ++i) s1 += S[i] * self_ws[i * 32 + lane];
        }
        __builtin_amdgcn_wave_barrier();
        if (lane < 32) S[lane] = s1;
        __builtin_amdgcn_wave_barrier();
        float ps = 0.f;
        if (lane < 48) {
            for (int i = 0; i < 32; ++i) ps += S[i] * pre_ws[i * 48 + lane];
            P[lane] = ps;                               // P[32:48) = gate pre-activation for wave1
        }
        __builtin_amdgcn_wave_barrier();
        float sc = (lane < 32) ? siluf(ps) : 0.f;
        if (lane < 32) S[lane] = sc;
        __builtin_amdgcn_wave_barrier();
        float s2 = 0.f;
        if (lane < 32) { for (int i = 0; i < 32; ++i) s2 += S[i] * post_ws[i * 32 + lane]; }
        float mu = s2;
        mu += __shfl_xor(mu, 1, 32); mu += __shfl_xor(mu, 2, 32);
        mu += __shfl_xor(mu, 4, 32); mu += __shfl_xor(mu, 8, 32); mu += __shfl_xor(mu, 16, 32);
        mu *= (1.0f / 32.0f);
        float t = s2 - mu;
        float var = t * t;
        var += __shfl_xor(var, 1, 32); var += __shfl_xor(var, 2, 32);
        var += __shfl_xor(var, 4, 32); var += __shfl_xor(var, 8, 32); var += __shfl_xor(var, 16, 32);
        var *= (1.0f / 32.0f);
        if (lane < 32) sln = t * rsqrtf(var + 1e-5f) * ln_g[lane] + ln_b[lane];
    } else {
        // --- v-chain (up to the gate dependency) ---
        float v1 = 0.f;
        if (lane < 48) {
            for (int i = 0; i < 32; ++i) v1 += M[32 + c * 32 + i] * w01[i * 16 + o];
            for (int v = 0; v < 16; ++v) v1 += M[144 + c * 16 + v] * w10[v * 16 + o];
            for (int v = 0; v < 16; ++v) v1 += M[192 + c * 16 + v] * w12[v * 16 + o];
            for (int v = 0; v < 16; ++v) v1 += Vt[c * 16 + v] * self_wv[v * 16 + o];
        }
        __builtin_amdgcn_wave_barrier();
        if (lane < 48) Vt[lane] = v1;
        __builtin_amdgcn_wave_barrier();
        if (lane < 48) {
            for (int v = 0; v < 16; ++v) pv += Vt[c * 16 + v] * pre_wv[v * 16 + o];
        }
    }
    __syncthreads();                                   // #3: P (gate) ready for wave1

    float v3 = 0.f;
    if (wv == 1) {
        float v2 = (lane < 48) ? pv * sigmoidf_(P[32 + o]) : 0.f;
        __builtin_amdgcn_wave_barrier();
        if (lane < 48) Vt[lane] = v2;
        __builtin_amdgcn_wave_barrier();
        if (lane < 48) { for (int v = 0; v < 16; ++v) v3 += Vt[c * 16 + v] * post_wv[v * 16 + o]; }
        __builtin_amdgcn_wave_barrier();
        if (lane < 48) Vt[lane] = v3;
        __builtin_amdgcn_wave_barrier();
        if (lane < 16) {
            float vx = Vt[lane], vy = Vt[16 + lane], vz = Vt[32 + lane];
            P[lane] = sqrtf(vx * vx + vy * vy + vz * vz + 1e-12f);
        }
        __builtin_amdgcn_wave_barrier();
        if (lane < 16) {
            float x = g_b1[lane];
            for (int mm = 0; mm < 16; ++mm) x += P[mm] * g_w1[mm * 16 + lane];
            P[16 + lane] = siluf(x);
        }
    }
    __syncthreads();                                   // #4: d1 ready for wave0

    if (wv == 0) {
        if (lane < 32) {
            float dl = g_b2[lane];
            for (int oo = 0; oo < 16; ++oo) dl += P[16 + oo] * g_w2[oo * 32 + lane];
            float sfin = sln + dl;
            if (out) out[(size_t)n * 80 + lane] = sfin;
            else     sNew[(size_t)n * 32 + lane] = sfin;
        }
    } else {
        if (lane < 48) {
            if (out) out[(size_t)n * 80 + 32 + o * 3 + c] = v3;
            else     vNew[(size_t)n * 48 + o * 3 + c] = v3;
        }
    }
}

extern "C" void kernel_launch(void* const* d_in, const int* in_sizes, int n_in,
                              void* d_out, int out_size, void* d_ws, size_t ws_size,
                              hipStream_t stream) {
    auto F = [&](int i) { return (const float*)d_in[i]; };
    const int* z  = (const int*)d_in[31];
    const int* ei = (const int*)d_in[32];
    int N = in_sizes[0] / 3;
    int E = in_sizes[1];

    char* w = (char*)d_ws;
    size_t off = 0;
    auto take = [&](size_t bytes) { size_t cur = off; off += (bytes + 255) & ~(size_t)255; return cur; };
    uint4* recH    = (uint4*)(w + take((size_t)E * 32));
    int2*  rec_src = (int2*)(w + take((size_t)E * 8));
    int*   loc_dst = (int*)(w + take((size_t)E * 4));
    int*   loc_src = (int*)(w + take((size_t)E * 4));
    float* tab     = (float*)(w + take((size_t)TTAB * 40 * 4));
    int* cnt_dst   = (int*)(w + take((size_t)2 * N * 4));
    int* cnt_src   = cnt_dst + N;
    int* row_dst   = (int*)(w + take((size_t)(N + 1) * 4));
    int* row_src   = (int*)(w + take((size_t)(N + 1) * 4));
    float* sA      = (float*)(w + take((size_t)N * 32 * 4));
    float* vA      = (float*)(w + take((size_t)N * 48 * 4));
    float* sB      = (float*)(w + take((size_t)N * 32 * 4));
    float* vB      = (float*)(w + take((size_t)N * 48 * 4));

    hipMemsetAsync(cnt_dst, 0, (size_t)2 * N * 4, stream);

    int nbc = (E + 255) / 256;
    k_tabcount<<<TTAB + nbc, 256, 0, stream>>>(F(8), F(9), F(10), F(11),
                                               F(12), F(13), F(4), F(5), tab,
                                               ei, cnt_dst, cnt_src, loc_dst, loc_src, E);
    k_scan2<<<2, 1024, 0, stream>>>(cnt_dst, row_dst, cnt_src, row_src, N);
    k_edge_fill<<<nbc, 256, 0, stream>>>(F(0), F(1), ei, tab, z,
                                         row_dst, row_src, loc_dst, loc_src,
                                         recH, rec_src, E);

    int nb = (N + 3) / 4;
    k_aggr<<<nb, 256, 0, stream>>>(row_src, rec_src, z, tab, F(3), F(2),
                                   F(6), F(7), sA, vA, N);

    float* sIn = sA; float* vIn = vA;
    float* sOut = sB; float* vOut = vB;
    for (int li = 0; li < 4; ++li) {
        float* outp = (li == 3) ? (float*)d_out : nullptr;
        k_layer<<<N, 128, 0, stream>>>(row_dst, recH,
                                        sIn, vIn,
                                        F(14) + li * 32 * 32, F(15) + li * 16 * 32,
                                        F(16) + li * 32 * 16, F(17) + li * 16 * 16,
                                        F(18) + li * 16 * 16,
                                        F(19) + li * 32 * 32, F(20) + li * 16 * 16,
                                        F(21) + li * 32 * 48, F(22) + li * 16 * 16,
                                        F(23) + li * 32 * 32, F(24) + li * 16 * 16,
                                        F(25) + li * 32, F(26) + li * 32,
                                        F(27) + li * 16 * 16, F(28) + li * 16,
                                        F(29) + li * 16 * 32, F(30) + li * 32,
                                        sOut, vOut, outp, N);
        float* ts = sIn; sIn = sOut; sOut = ts;
        float* tv = vIn; vIn = vOut; vOut = tv;
    }
}

// Round 10
// 587.820 us; speedup vs baseline: 1.0197x; 1.0197x over previous
//
#include <hip/hip_runtime.h>
#include <hip/hip_fp16.h>

#define RCUT 3.5f
#define TTAB 2048

static __device__ __forceinline__ float sigmoidf_(float x) { return 1.0f / (1.0f + expf(-x)); }
static __device__ __forceinline__ float siluf(float x) { return x / (1.0f + expf(-x)); }
// nan_to_num: 0 for NaN/Inf (bit-pattern test, fast-math immune)
static __device__ __forceinline__ float san(float x) {
    return ((__float_as_uint(x) & 0x7F800000u) != 0x7F800000u) ? x : 0.f;
}
// fp16 pack/unpack for the layer-invariant edge records
static __device__ __forceinline__ unsigned pk(float a, float b) {
    __half2 h = __floats2half2_rn(a, b);
    return *reinterpret_cast<unsigned*>(&h);
}
static __device__ __forceinline__ float2 upk(unsigned u) {
    __half2 h = *reinterpret_cast<__half2*>(&u);
    return __half22float2(h);
}

// ---------------- fused: radial table (blocks 0..TTAB) + degree count/slot (rest) ------------
// k_count's atomicAdd RETURN VALUE is the edge's local slot -> stored coalesced by edge id.
__global__ __launch_bounds__(256) void k_tabcount(const float* means, const float* betas,
                        const float* rad_w1, const float* rad_b1,
                        const float* rad_w2, const float* rad_b2,
                        const float* ne_dw, const float* ne_db,
                        float* tab,
                        const int* ei, int* cnt_dst, int* cnt_src,
                        int* loc_dst, int* loc_src, int E) {
    if (blockIdx.x >= TTAB) {
        int e = (blockIdx.x - TTAB) * 256 + threadIdx.x;
        if (e < E) {
            loc_dst[e] = atomicAdd(cnt_dst + ei[E + e], 1);
            loc_src[e] = atomicAdd(cnt_src + ei[e], 1);
        }
        return;
    }
    __shared__ float red[3][4];
    int i = blockIdx.x;
    int h = threadIdx.x;
    int lane = h & 63, wv = h >> 6;
    float d  = (float)i * (RCUT / (float)(TTAB - 1));
    float dc = fmaxf(d, 1e-6f);
    float C  = (dc < RCUT) ? 0.5f * (cosf(dc * (3.14159265358979f / RCUT)) + 1.0f) : 0.0f;
    float ex = expf(-(5.0f / RCUT) * dc);
    float rbf[8];
#pragma unroll
    for (int nn = 0; nn < 8; ++nn) {
        float b = fmaxf(betas[nn], 1e-6f);
        float t = ex - means[nn];
        rbf[nn] = C * expf(-b * t * t);
    }
    float con[3];
#pragma unroll
    for (int l = 0; l < 3; ++l) {
        float cc = rad_b1[l * 256 + h];
#pragma unroll
        for (int nn = 0; nn < 8; ++nn) cc += rbf[nn] * rad_w1[(l * 8 + nn) * 256 + h];
        con[l] = siluf(cc) * rad_w2[l * 256 + h];
    }
#pragma unroll
    for (int m = 1; m < 64; m <<= 1) {
        con[0] += __shfl_xor(con[0], m, 64);
        con[1] += __shfl_xor(con[1], m, 64);
        con[2] += __shfl_xor(con[2], m, 64);
    }
    if (lane == 0) { red[0][wv] = con[0]; red[1][wv] = con[1]; red[2][wv] = con[2]; }
    __syncthreads();
    if (h < 3)
        tab[i * 40 + h] = rad_b2[h] + red[h][0] + red[h][1] + red[h][2] + red[h][3];
    else if (h == 3)
        tab[i * 40 + 3] = 0.f;
    else if (h < 36) {
        int c = h - 4;
        float wvv = ne_db[c];
#pragma unroll
        for (int nn = 0; nn < 8; ++nn) wvv += rbf[nn] * ne_dw[nn * 32 + c];
        tab[i * 40 + h] = wvv * C;   // W includes cutoff_fn(d)
    } else if (h < 40)
        tab[i * 40 + h] = 0.f;
}

// ---------------- dual exclusive scan: per-thread chunk + single block scan ------------------
__global__ __launch_bounds__(1024) void k_scan2(const int* cntA, int* rowA,
                        const int* cntB, int* rowB, int n) {
    __shared__ int wsum[16];
    const int* cnt = blockIdx.x ? cntB : cntA;
    int* rowptr    = blockIdx.x ? rowB : rowA;
    int tid = threadIdx.x, lane = tid & 63, wv = tid >> 6;
    int per = (n + 1023) >> 10;
    int beg = tid * per; if (beg > n) beg = n;
    int end = beg + per; if (end > n) end = n;
    int s = 0;
    for (int i = beg; i < end; ++i) s += cnt[i];
    int v = s;
#pragma unroll
    for (int m = 1; m < 64; m <<= 1) {
        int t = __shfl_up(v, m, 64);
        if (lane >= m) v += t;
    }
    if (lane == 63) wsum[wv] = v;
    __syncthreads();
    int wbase = 0;
    for (int j = 0; j < wv; ++j) wbase += wsum[j];
    int run = wbase + v - s;               // exclusive prefix for this thread's chunk
    for (int i = beg; i < end; ++i) {
        int val = cnt[i];
        rowptr[i] = run;
        run += val;
    }
    if (tid == 1023) rowptr[n] = run;
}

// ---------------- edge-compute + scatter, NO atomics (slots precomputed) ---------------------
// recH (2x uint4 = 32 B/edge):
//   [0]: pk(ae0,e1x) pk(e1y,e1z) col pk(q12,q22)    <- wave0's half
//   [1]: pk(q00,q01) pk(q02,q11) col 0              <- wave1's half
// slot = row[node] + loc[e]; all gathers are L2-resident (pos 240KB, row 80KB, tab 320KB).
__global__ void k_edge_fill(const float* pos, const float* alpha,
                            const int* ei, const float* tab, const int* z,
                            const int* row_dst, const int* row_src,
                            const int* loc_dst, const int* loc_src,
                            uint4* recH, int2* rec_src, int E) {
    int e = blockIdx.x * blockDim.x + threadIdx.x;
    if (e >= E) return;
    int sn = ei[e], dn = ei[E + e];
    float rx = pos[dn * 3]     - pos[sn * 3];
    float ry = pos[dn * 3 + 1] - pos[sn * 3 + 1];
    float rz = pos[dn * 3 + 2] - pos[sn * 3 + 2];
    float d = sqrtf(rx * rx + ry * ry + rz * rz + 1e-12f);
    float inv = 1.0f / d;
    rx *= inv; ry *= inv; rz *= inv;
    float u = fminf(d, RCUT) * ((float)(TTAB - 1) / RCUT);
    int i0 = (int)u; if (i0 > TTAB - 2) i0 = TTAB - 2;
    float f = u - (float)i0;
    const float* t0 = tab + i0 * 40;
    float c0 = t0[0] + f * (t0[40] - t0[0]);
    float c1 = t0[1] + f * (t0[41] - t0[1]);
    float c2 = t0[2] + f * (t0[42] - t0[2]);
    float al = alpha[e];
    float ae0 = san(al * c0);
    float k1 = 1.73205081f * al * c1;      // sqrt(3)*alpha*coeff1
    float k2 = al * c2;
    float e20 = san(5.47722558f * rx * ry * k2);                             // sqrt(30) xy
    float e21 = san(5.47722558f * ry * rz * k2);
    float e22 = san(1.58113883f * (2.f * rz * rz - rx * rx - ry * ry) * k2); // sqrt(2.5)
    float e23 = san(5.47722558f * rx * rz * k2);
    float e24 = san(2.73861279f * (rx * rx - ry * ry) * k2);                 // sqrt(7.5)
    const float S2 = 0.70710678f, S6 = 0.40824829f;
    float q00 = -S6 * e22 + S2 * e24;
    float q01 = S2 * e20;
    float q02 = S2 * e23;
    float q11 = -S6 * e22 - S2 * e24;
    float q12 = S2 * e21;
    float q22 = 2.f * S6 * e22;
    int p  = row_dst[dn] + loc_dst[e];
    int p2 = row_src[sn] + loc_src[e];
    uint4 r0, r1;
    r0.x = pk(ae0, san(k1 * rx));
    r0.y = pk(san(k1 * ry), san(k1 * rz));
    r0.z = (unsigned)sn;
    r0.w = pk(q12, q22);
    r1.x = pk(q00, q01);
    r1.y = pk(q02, q11);
    r1.z = (unsigned)sn;
    r1.w = 0u;
    recH[(size_t)p * 2]     = r0;
    recH[(size_t)p * 2 + 1] = r1;
    float uc = fminf(u, (float)(TTAB - 1) - 1e-3f);
    rec_src[p2] = make_int2(__float_as_int(uc), z[dn]);
}

// ---------------- aggr (src-sorted records) + initial node embed -----------------------------
// wave-synchronous: all LDS is per-wave
__global__ __launch_bounds__(256) void k_aggr(const int* row_src, const int2* recs,
        const int* z, const float* tab, const float* ne_emb, const float* atom_emb,
        const float* ne_cw, const float* ne_cb,
        float* sbuf, float* vbuf, int N) {
    __shared__ float part[4][64];
    __shared__ float cat[4][64];
    int wv = threadIdx.x >> 6, lane = threadIdx.x & 63;
    int n = blockIdx.x * 4 + wv;
    bool act = n < N;
    int g = lane >> 5, li = lane & 31;
    float acc = 0.f;
    if (act) {
        int r0 = row_src[n], r1 = row_src[n + 1];
        int half = (r1 - r0) >> 1;
        int kb = g ? (r0 + half) : r0;
        int ke = g ? r1 : (r0 + half);
        int k = kb;
        for (; k + 2 <= ke; k += 2) {
            int2 rA = recs[k], rB = recs[k + 1];
            float uA = __int_as_float(rA.x), uB = __int_as_float(rB.x);
            int iA = (int)uA, iB = (int)uB;
            float fA = uA - (float)iA, fB = uB - (float)iB;
            float wA0 = tab[iA * 40 + 4 + li], wA1 = tab[iA * 40 + 44 + li];
            float wB0 = tab[iB * 40 + 4 + li], wB1 = tab[iB * 40 + 44 + li];
            float eA = ne_emb[rA.y * 32 + li], eB = ne_emb[rB.y * 32 + li];
            acc += (wA0 + fA * (wA1 - wA0)) * eA + (wB0 + fB * (wB1 - wB0)) * eB;
        }
        for (; k < ke; ++k) {
            int2 r = recs[k];
            float u = __int_as_float(r.x);
            int i0 = (int)u; float f = u - (float)i0;
            float w0 = tab[i0 * 40 + 4 + li], w1 = tab[i0 * 40 + 44 + li];
            acc += (w0 + f * (w1 - w0)) * ne_emb[r.y * 32 + li];
        }
    }
    part[wv][lane] = acc;
    __builtin_amdgcn_wave_barrier();
    if (act && lane < 32) {
        cat[wv][lane] = atom_emb[z[n] * 32 + lane];
        cat[wv][32 + lane] = part[wv][lane] + part[wv][32 + lane];
    }
    __builtin_amdgcn_wave_barrier();
    if (act && lane < 32) {
        float soa = 0.f, sob = ne_cb[lane];
        for (int j = 0; j < 64; j += 2) {
            soa += cat[wv][j] * ne_cw[j * 32 + lane];
            sob += cat[wv][j + 1] * ne_cw[(j + 1) * 32 + lane];
        }
        sbuf[n * 32 + lane] = soa + sob;
    }
    if (act && lane < 48) vbuf[n * 48 + lane] = 0.f;
}

// half-block s accumulate (2 edges per lane-half)
#define SBLK2(BIDX, X0, X1)                                                             \
    {                                                                                   \
        int e_ = ((BIDX) << 2) + 2 * h;                                                 \
        float4 A0 = eA[e_], A1 = eA[e_ + 1];                                            \
        a0  += X0 * A0.x + X1 * A1.x;                                                   \
        a1x += X0 * A0.y + X1 * A1.y;                                                   \
        a1y += X0 * A0.z + X1 * A1.z;                                                   \
        a1z += X0 * A0.w + X1 * A1.w;                                                   \
    }

// one-edge v accumulate (edge slot g of block)
#define VBLK1(BIDX, U, V, W)                                                            \
    {                                                                                   \
        int e_ = ((BIDX) << 2) + g;                                                     \
        float4 Aa = eA[e_];                                                             \
        float4 Qa = eQ[e_];                                                             \
        float2 Ra = eR[e_];                                                             \
        adv += U * Aa.y + V * Aa.z + W * Aa.w;                                          \
        a2x += U * Aa.x; a2y += V * Aa.x; a2z += W * Aa.x;                              \
        a3x += Qa.x * U + Qa.y * V + Qa.z * W;                                          \
        a3y += Qa.y * U + Qa.w * V + Ra.x * W;                                          \
        a3z += Qa.z * U + Ra.x * V + Ra.y * W;                                          \
    }

// ---------------- fused layer: 1 node / 128-thread block, specialized waves ------------------
// wave0 = s-path, wave1 = v-path (round-8 structure, proven 74us; round-9 lesson: deeper
// pipelines / duplicated staging cost occupancy and regress -> keep depth-2 + shared staging).
// Node update: split-K across idle lane-half (s1, s2) + partial accumulators everywhere to
// shorten the serial FMA dependency chains (f32 re-association only).
__global__ __launch_bounds__(128) void k_layer(const int* __restrict__ row_dst,
        const uint4* __restrict__ recH,
        const float* __restrict__ sOld, const float* __restrict__ vOld,
        const float* w00, const float* w110, const float* w01,
        const float* w10, const float* w12,
        const float* self_ws, const float* self_wv,
        const float* pre_ws, const float* pre_wv,
        const float* post_ws, const float* post_wv,
        const float* ln_g, const float* ln_b,
        const float* g_w1, const float* g_b1,
        const float* g_w2, const float* g_b2,
        float* __restrict__ sNew, float* __restrict__ vNew,
        float* __restrict__ out, int N) {
    __shared__ __align__(16) float4 eA[64];
    __shared__ __align__(16) float4 eQ[64];
    __shared__ __align__(16) float2 eR[64];
    __shared__ __align__(16) int    eC[64];
    __shared__ float M[240];
    __shared__ float S[32], Vt[48], P[48];
    int wv = threadIdx.x >> 6, lane = threadIdx.x & 63;
    int n = blockIdx.x;
    int r0 = row_dst[n], r1 = row_dst[n + 1];
    int deg = r1 - r0;
    int cap = deg < 64 ? deg : 64;
    int nblk = cap >> 2;

    // ---- staging: wave0 -> eA,eR,eC + S ; wave1 -> eQ + Vt ----
    if (wv == 0) {
        if (lane < cap) {
            uint4 rA = recH[(size_t)(r0 + lane) * 2];
            float2 p0 = upk(rA.x), p1 = upk(rA.y), p3 = upk(rA.w);
            eA[lane] = make_float4(p0.x, p0.y, p1.x, p1.y);
            eR[lane] = make_float2(p3.x, p3.y);
            eC[lane] = (int)rA.z;
        }
        if (lane < 32) S[lane] = sOld[(size_t)n * 32 + lane];
    } else {
        if (lane < cap) {
            uint4 rB = recH[(size_t)(r0 + lane) * 2 + 1];
            float2 q0 = upk(rB.x), q1 = upk(rB.y);
            eQ[lane] = make_float4(q0.x, q0.y, q1.x, q1.y);
        }
        if (lane < 48) {
            int c_ = lane >> 4, o_ = lane & 15;
            Vt[c_ * 16 + o_] = vOld[(size_t)n * 48 + o_ * 3 + c_];
        }
    }
    __syncthreads();                                   // #1: staging complete

    const int4* eC4 = (const int4*)eC;
    if (wv == 0) {
        // ================= s-path wave =================
        int h = lane >> 5, d = lane & 31;
        float a0 = 0.f, a1x = 0.f, a1y = 0.f, a1z = 0.f;
        float xA0 = 0.f, xA1 = 0.f, xB0 = 0.f, xB1 = 0.f;
        if (nblk > 0) {
            int4 c4 = eC4[0];
            xA0 = sOld[(h ? c4.z : c4.x) * 32 + d];
            xA1 = sOld[(h ? c4.w : c4.y) * 32 + d];
        }
        if (nblk > 1) {
            int4 c4 = eC4[1];
            xB0 = sOld[(h ? c4.z : c4.x) * 32 + d];
            xB1 = sOld[(h ? c4.w : c4.y) * 32 + d];
        }
        int b = 0;
        for (; b + 2 <= nblk; b += 2) {
            int4 c40 = (b + 2 < nblk) ? eC4[b + 2] : make_int4(0, 0, 0, 0);
            int4 c41 = (b + 3 < nblk) ? eC4[b + 3] : make_int4(0, 0, 0, 0);
            float t0 = sOld[(h ? c40.z : c40.x) * 32 + d];
            float t1 = sOld[(h ? c40.w : c40.y) * 32 + d];
            float u0 = sOld[(h ? c41.z : c41.x) * 32 + d];
            float u1 = sOld[(h ? c41.w : c41.y) * 32 + d];
            SBLK2(b, xA0, xA1);
            SBLK2(b + 1, xB0, xB1);
            xA0 = t0; xA1 = t1; xB0 = u0; xB1 = u1;
        }
        if (b < nblk) { SBLK2(b, xA0, xA1); }
        for (int k = r0 + (nblk << 2); k < r1; ++k) {   // tail (+ deg>64 overflow), half 0 only
            if (h == 0) {
                uint4 rA = recH[(size_t)k * 2];
                float2 p0 = upk(rA.x), p1 = upk(rA.y);
                int cc = (int)rA.z;
                float xx = sOld[cc * 32 + d];
                a0 += xx * p0.x; a1x += xx * p0.y; a1y += xx * p1.x; a1z += xx * p1.y;
            }
        }
        a0  += __shfl_xor(a0, 32, 64);
        a1x += __shfl_xor(a1x, 32, 64);
        a1y += __shfl_xor(a1y, 32, 64);
        a1z += __shfl_xor(a1z, 32, 64);
        if (lane < 32) {
            M[lane] = a0; M[32 + lane] = a1x; M[64 + lane] = a1y; M[96 + lane] = a1z;
        }
    } else {
        // ================= v-path wave =================
        int g = lane >> 4, m = lane & 15;
        float adv = 0.f, a2x = 0.f, a2y = 0.f, a2z = 0.f, a3x = 0.f, a3y = 0.f, a3z = 0.f;
        float uA = 0.f, vA = 0.f, wA = 0.f, uB = 0.f, vB = 0.f, wB = 0.f;
        if (nblk > 0) {
            const float* vp = vOld + (size_t)eC[g] * 48 + m * 3;
            uA = vp[0]; vA = vp[1]; wA = vp[2];
        }
        if (nblk > 1) {
            const float* vp = vOld + (size_t)eC[4 + g] * 48 + m * 3;
            uB = vp[0]; vB = vp[1]; wB = vp[2];
        }
        int b = 0;
        for (; b + 2 <= nblk; b += 2) {
            int cn0 = (b + 2 < nblk) ? eC[(b + 2) * 4 + g] : 0;
            int cn1 = (b + 3 < nblk) ? eC[(b + 3) * 4 + g] : 0;
            const float* q0 = vOld + (size_t)cn0 * 48 + m * 3;
            const float* q1 = vOld + (size_t)cn1 * 48 + m * 3;
            float tu = q0[0], tv = q0[1], tw = q0[2];
            float su = q1[0], sv = q1[1], sw = q1[2];
            VBLK1(b, uA, vA, wA);
            VBLK1(b + 1, uB, vB, wB);
            uA = tu; vA = tv; wA = tw; uB = su; vB = sv; wB = sw;
        }
        if (b < nblk) { VBLK1(b, uA, vA, wA); }
        for (int k = r0 + (nblk << 2); k < r1; ++k) {   // tail, slot group 0 only
            if (g == 0) {
                uint4 rA = recH[(size_t)k * 2];
                uint4 rB = recH[(size_t)k * 2 + 1];
                float2 p0 = upk(rA.x), p1 = upk(rA.y), p3 = upk(rA.w);
                float2 q0 = upk(rB.x), q1 = upk(rB.y);
                int cc = (int)rA.z;
                const float* vp = vOld + (size_t)cc * 48 + m * 3;
                float vx = vp[0], vy = vp[1], vz = vp[2];
                adv += vx * p0.y + vy * p1.x + vz * p1.y;
                a2x += vx * p0.x; a2y += vy * p0.x; a2z += vz * p0.x;
                a3x += q0.x * vx + q0.y * vy + q1.x * vz;
                a3y += q0.y * vx + q1.y * vy + p3.x * vz;
                a3z += q1.x * vx + p3.x * vy + p3.y * vz;
            }
        }
        adv += __shfl_xor(adv, 16, 64); adv += __shfl_xor(adv, 32, 64);
        a2x += __shfl_xor(a2x, 16, 64); a2x += __shfl_xor(a2x, 32, 64);
        a2y += __shfl_xor(a2y, 16, 64); a2y += __shfl_xor(a2y, 32, 64);
        a2z += __shfl_xor(a2z, 16, 64); a2z += __shfl_xor(a2z, 32, 64);
        a3x += __shfl_xor(a3x, 16, 64); a3x += __shfl_xor(a3x, 32, 64);
        a3y += __shfl_xor(a3y, 16, 64); a3y += __shfl_xor(a3y, 32, 64);
        a3z += __shfl_xor(a3z, 16, 64); a3z += __shfl_xor(a3z, 32, 64);
        if (lane < 16) {
            M[128 + m] = adv;
            M[144 + m] = a2x; M[160 + m] = a2y; M[176 + m] = a2z;
            M[192 + m] = a3x; M[208 + m] = a3y; M[224 + m] = a3z;
        }
    }
    __syncthreads();                                   // #2: moments complete

    // ================= node update, split across the two waves =================
    float sln = 0.f, pv = 0.f;
    int c = lane >> 4, o16 = lane & 15;
    if (wv == 0) {
        // --- s-chain: split-K across lane halves + dual partial accumulators ---
        int h2 = lane >> 5, o = lane & 31;
        int ib = h2 * 16, vb = h2 * 8;
        float pa = 0.f, pb = 0.f;
#pragma unroll
        for (int i = 0; i < 16; i += 2) {
            pa += M[ib + i]     * w00[(ib + i) * 32 + o];
            pb += M[ib + i + 1] * w00[(ib + i + 1) * 32 + o];
        }
#pragma unroll
        for (int v = 0; v < 8; v += 2) {
            pa += M[128 + vb + v]     * w110[(vb + v) * 32 + o];
            pb += M[128 + vb + v + 1] * w110[(vb + v + 1) * 32 + o];
        }
#pragma unroll
        for (int i = 0; i < 16; i += 2) {
            pa += S[ib + i]     * self_ws[(ib + i) * 32 + o];
            pb += S[ib + i + 1] * self_ws[(ib + i + 1) * 32 + o];
        }
        float part = pa + pb;
        float s1 = part + __shfl_xor(part, 32, 64);
        __builtin_amdgcn_wave_barrier();
        if (lane < 32) S[lane] = s1;
        __builtin_amdgcn_wave_barrier();
        float ps = 0.f;
        if (lane < 48) {
            float qa = 0.f, qb = 0.f;
#pragma unroll
            for (int i = 0; i < 32; i += 2) {
                qa += S[i]     * pre_ws[i * 48 + lane];
                qb += S[i + 1] * pre_ws[(i + 1) * 48 + lane];
            }
            ps = qa + qb;
            P[lane] = ps;                               // P[32:48) = gate pre-activation for wave1
        }
        __builtin_amdgcn_wave_barrier();
        float sc = (lane < 32) ? siluf(ps) : 0.f;
        if (lane < 32) S[lane] = sc;
        __builtin_amdgcn_wave_barrier();
        // post: split-K across halves
        float ra = 0.f, rb = 0.f;
#pragma unroll
        for (int i = 0; i < 16; i += 2) {
            ra += S[ib + i]     * post_ws[(ib + i) * 32 + o];
            rb += S[ib + i + 1] * post_ws[(ib + i + 1) * 32 + o];
        }
        float pr = ra + rb;
        float s2 = pr + __shfl_xor(pr, 32, 64);
        float mu = s2;
        mu += __shfl_xor(mu, 1, 32); mu += __shfl_xor(mu, 2, 32);
        mu += __shfl_xor(mu, 4, 32); mu += __shfl_xor(mu, 8, 32); mu += __shfl_xor(mu, 16, 32);
        mu *= (1.0f / 32.0f);
        float t = s2 - mu;
        float var = t * t;
        var += __shfl_xor(var, 1, 32); var += __shfl_xor(var, 2, 32);
        var += __shfl_xor(var, 4, 32); var += __shfl_xor(var, 8, 32); var += __shfl_xor(var, 16, 32);
        var *= (1.0f / 32.0f);
        if (lane < 32) sln = t * rsqrtf(var + 1e-5f) * ln_g[lane] + ln_b[lane];
    } else {
        // --- v-chain (4 partial accumulators) ---
        float v1 = 0.f;
        if (lane < 48) {
            float va = 0.f, vbp = 0.f, vc = 0.f, vd = 0.f;
#pragma unroll
            for (int i = 0; i < 32; i += 2) {
                va  += M[32 + c * 32 + i]     * w01[i * 16 + o16];
                vbp += M[32 + c * 32 + i + 1] * w01[(i + 1) * 16 + o16];
            }
#pragma unroll
            for (int v = 0; v < 16; v += 2) {
                vc += M[144 + c * 16 + v]     * w10[v * 16 + o16];
                vd += M[144 + c * 16 + v + 1] * w10[(v + 1) * 16 + o16];
            }
#pragma unroll
            for (int v = 0; v < 16; v += 2) {
                va  += M[192 + c * 16 + v]     * w12[v * 16 + o16];
                vbp += M[192 + c * 16 + v + 1] * w12[(v + 1) * 16 + o16];
            }
#pragma unroll
            for (int v = 0; v < 16; v += 2) {
                vc += Vt[c * 16 + v]     * self_wv[v * 16 + o16];
                vd += Vt[c * 16 + v + 1] * self_wv[(v + 1) * 16 + o16];
            }
            v1 = (va + vbp) + (vc + vd);
        }
        __builtin_amdgcn_wave_barrier();
        if (lane < 48) Vt[lane] = v1;
        __builtin_amdgcn_wave_barrier();
        if (lane < 48) {
            float qa = 0.f, qb = 0.f;
#pragma unroll
            for (int v = 0; v < 16; v += 2) {
                qa += Vt[c * 16 + v]     * pre_wv[v * 16 + o16];
                qb += Vt[c * 16 + v + 1] * pre_wv[(v + 1) * 16 + o16];
            }
            pv = qa + qb;
        }
    }
    __syncthreads();                                   // #3: P (gate) ready for wave1

    float v3 = 0.f;
    if (wv == 1) {
        float v2 = (lane < 48) ? pv * sigmoidf_(P[32 + o16]) : 0.f;
        __builtin_amdgcn_wave_barrier();
        if (lane < 48) Vt[lane] = v2;
        __builtin_amdgcn_wave_barrier();
        if (lane < 48) {
            float qa = 0.f, qb = 0.f;
#pragma unroll
            for (int v = 0; v < 16; v += 2) {
                qa += Vt[c * 16 + v]     * post_wv[v * 16 + o16];
                qb += Vt[c * 16 + v + 1] * post_wv[(v + 1) * 16 + o16];
            }
            v3 = qa + qb;
        }
        __builtin_amdgcn_wave_barrier();
        if (lane < 48) Vt[lane] = v3;
        __builtin_amdgcn_wave_barrier();
        if (lane < 16) {
            float vx = Vt[lane], vy = Vt[16 + lane], vz = Vt[32 + lane];
            P[lane] = sqrtf(vx * vx + vy * vy + vz * vz + 1e-12f);
        }
        __builtin_amdgcn_wave_barrier();
        if (lane < 16) {
            float xa = g_b1[lane], xb = 0.f;
#pragma unroll
            for (int mm = 0; mm < 16; mm += 2) {
                xa += P[mm]     * g_w1[mm * 16 + lane];
                xb += P[mm + 1] * g_w1[(mm + 1) * 16 + lane];
            }
            P[16 + lane] = siluf(xa + xb);
        }
    }
    __syncthreads();                                   // #4: d1 ready for wave0

    if (wv == 0) {
        if (lane < 32) {
            float da = g_b2[lane], db = 0.f;
#pragma unroll
            for (int oo = 0; oo < 16; oo += 2) {
                da += P[16 + oo]     * g_w2[oo * 32 + lane];
                db += P[16 + oo + 1] * g_w2[(oo + 1) * 32 + lane];
            }
            float sfin = sln + (da + db);
            if (out) out[(size_t)n * 80 + lane] = sfin;
            else     sNew[(size_t)n * 32 + lane] = sfin;
        }
    } else {
        if (lane < 48) {
            if (out) out[(size_t)n * 80 + 32 + o16 * 3 + c] = v3;
            else     vNew[(size_t)n * 48 + o16 * 3 + c] = v3;
        }
    }
}

extern "C" void kernel_launch(void* const* d_in, const int* in_sizes, int n_in,
                              void* d_out, int out_size, void* d_ws, size_t ws_size,
                              hipStream_t stream) {
    auto F = [&](int i) { return (const float*)d_in[i]; };
    const int* z  = (const int*)d_in[31];
    const int* ei = (const int*)d_in[32];
    int N = in_sizes[0] / 3;
    int E = in_sizes[1];

    char* w = (char*)d_ws;
    size_t off = 0;
    auto take = [&](size_t bytes) { size_t cur = off; off += (bytes + 255) & ~(size_t)255; return cur; };
    uint4* recH    = (uint4*)(w + take((size_t)E * 32));
    int2*  rec_src = (int2*)(w + take((size_t)E * 8));
    int*   loc_dst = (int*)(w + take((size_t)E * 4));
    int*   loc_src = (int*)(w + take((size_t)E * 4));
    float* tab     = (float*)(w + take((size_t)TTAB * 40 * 4));
    int* cnt_dst   = (int*)(w + take((size_t)2 * N * 4));
    int* cnt_src   = cnt_dst + N;
    int* row_dst   = (int*)(w + take((size_t)(N + 1) * 4));
    int* row_src   = (int*)(w + take((size_t)(N + 1) * 4));
    float* sA      = (float*)(w + take((size_t)N * 32 * 4));
    float* vA      = (float*)(w + take((size_t)N * 48 * 4));
    float* sB      = (float*)(w + take((size_t)N * 32 * 4));
    float* vB      = (float*)(w + take((size_t)N * 48 * 4));

    hipMemsetAsync(cnt_dst, 0, (size_t)2 * N * 4, stream);

    int nbc = (E + 255) / 256;
    k_tabcount<<<TTAB + nbc, 256, 0, stream>>>(F(8), F(9), F(10), F(11),
                                               F(12), F(13), F(4), F(5), tab,
                                               ei, cnt_dst, cnt_src, loc_dst, loc_src, E);
    k_scan2<<<2, 1024, 0, stream>>>(cnt_dst, row_dst, cnt_src, row_src, N);
    k_edge_fill<<<nbc, 256, 0, stream>>>(F(0), F(1), ei, tab, z,
                                         row_dst, row_src, loc_dst, loc_src,
                                         recH, rec_src, E);

    int nb = (N + 3) / 4;
    k_aggr<<<nb, 256, 0, stream>>>(row_src, rec_src, z, tab, F(3), F(2),
                                   F(6), F(7), sA, vA, N);

    float* sIn = sA; float* vIn = vA;
    float* sOut = sB; float* vOut = vB;
    for (int li = 0; li < 4; ++li) {
        float* outp = (li == 3) ? (float*)d_out : nullptr;
        k_layer<<<N, 128, 0, stream>>>(row_dst, recH,
                                        sIn, vIn,
                                        F(14) + li * 32 * 32, F(15) + li * 16 * 32,
                                        F(16) + li * 32 * 16, F(17) + li * 16 * 16,
                                        F(18) + li * 16 * 16,
                                        F(19) + li * 32 * 32, F(20) + li * 16 * 16,
                                        F(21) + li * 32 * 48, F(22) + li * 16 * 16,
                                        F(23) + li * 32 * 32, F(24) + li * 16 * 16,
                                        F(25) + li * 32, F(26) + li * 32,
                                        F(27) + li * 16 * 16, F(28) + li * 16,
                                        F(29) + li * 16 * 32, F(30) + li * 32,
                                        sOut, vOut, outp, N);
        float* ts = sIn; sIn = sOut; sOut = ts;
        float* tv = vIn; vIn = vOut; vOut = tv;
    }
}

// Round 11
// 528.290 us; speedup vs baseline: 1.1346x; 1.1127x over previous
//
#include <hip/hip_runtime.h>
#include <hip/hip_fp16.h>

#define RCUT 3.5f
#define TTAB 2048

static __device__ __forceinline__ float sigmoidf_(float x) { return 1.0f / (1.0f + expf(-x)); }
static __device__ __forceinline__ float siluf(float x) { return x / (1.0f + expf(-x)); }
// nan_to_num: 0 for NaN/Inf (bit-pattern test, fast-math immune)
static __device__ __forceinline__ float san(float x) {
    return ((__float_as_uint(x) & 0x7F800000u) != 0x7F800000u) ? x : 0.f;
}
// fp16 pack/unpack for the layer-invariant edge records
static __device__ __forceinline__ unsigned pk(float a, float b) {
    __half2 h = __floats2half2_rn(a, b);
    return *reinterpret_cast<unsigned*>(&h);
}
static __device__ __forceinline__ float2 upk(unsigned u) {
    __half2 h = *reinterpret_cast<__half2*>(&u);
    return __half22float2(h);
}

// ---------------- fused: radial table (blocks 0..TTAB) + degree count/slot (rest) ------------
// k_count's atomicAdd RETURN VALUE is the edge's local slot -> stored coalesced by edge id.
__global__ __launch_bounds__(256) void k_tabcount(const float* means, const float* betas,
                        const float* rad_w1, const float* rad_b1,
                        const float* rad_w2, const float* rad_b2,
                        const float* ne_dw, const float* ne_db,
                        float* tab,
                        const int* ei, int* cnt_dst, int* cnt_src,
                        int* loc_dst, int* loc_src, int E) {
    if (blockIdx.x >= TTAB) {
        int e = (blockIdx.x - TTAB) * 256 + threadIdx.x;
        if (e < E) {
            loc_dst[e] = atomicAdd(cnt_dst + ei[E + e], 1);
            loc_src[e] = atomicAdd(cnt_src + ei[e], 1);
        }
        return;
    }
    __shared__ float red[3][4];
    int i = blockIdx.x;
    int h = threadIdx.x;
    int lane = h & 63, wv = h >> 6;
    float d  = (float)i * (RCUT / (float)(TTAB - 1));
    float dc = fmaxf(d, 1e-6f);
    float C  = (dc < RCUT) ? 0.5f * (cosf(dc * (3.14159265358979f / RCUT)) + 1.0f) : 0.0f;
    float ex = expf(-(5.0f / RCUT) * dc);
    float rbf[8];
#pragma unroll
    for (int nn = 0; nn < 8; ++nn) {
        float b = fmaxf(betas[nn], 1e-6f);
        float t = ex - means[nn];
        rbf[nn] = C * expf(-b * t * t);
    }
    float con[3];
#pragma unroll
    for (int l = 0; l < 3; ++l) {
        float cc = rad_b1[l * 256 + h];
#pragma unroll
        for (int nn = 0; nn < 8; ++nn) cc += rbf[nn] * rad_w1[(l * 8 + nn) * 256 + h];
        con[l] = siluf(cc) * rad_w2[l * 256 + h];
    }
#pragma unroll
    for (int m = 1; m < 64; m <<= 1) {
        con[0] += __shfl_xor(con[0], m, 64);
        con[1] += __shfl_xor(con[1], m, 64);
        con[2] += __shfl_xor(con[2], m, 64);
    }
    if (lane == 0) { red[0][wv] = con[0]; red[1][wv] = con[1]; red[2][wv] = con[2]; }
    __syncthreads();
    if (h < 3)
        tab[i * 40 + h] = rad_b2[h] + red[h][0] + red[h][1] + red[h][2] + red[h][3];
    else if (h == 3)
        tab[i * 40 + 3] = 0.f;
    else if (h < 36) {
        int c = h - 4;
        float wvv = ne_db[c];
#pragma unroll
        for (int nn = 0; nn < 8; ++nn) wvv += rbf[nn] * ne_dw[nn * 32 + c];
        tab[i * 40 + h] = wvv * C;   // W includes cutoff_fn(d)
    } else if (h < 40)
        tab[i * 40 + h] = 0.f;
}

// ---------------- dual exclusive scan: per-thread chunk + single block scan ------------------
__global__ __launch_bounds__(1024) void k_scan2(const int* cntA, int* rowA,
                        const int* cntB, int* rowB, int n) {
    __shared__ int wsum[16];
    const int* cnt = blockIdx.x ? cntB : cntA;
    int* rowptr    = blockIdx.x ? rowB : rowA;
    int tid = threadIdx.x, lane = tid & 63, wv = tid >> 6;
    int per = (n + 1023) >> 10;
    int beg = tid * per; if (beg > n) beg = n;
    int end = beg + per; if (end > n) end = n;
    int s = 0;
    for (int i = beg; i < end; ++i) s += cnt[i];
    int v = s;
#pragma unroll
    for (int m = 1; m < 64; m <<= 1) {
        int t = __shfl_up(v, m, 64);
        if (lane >= m) v += t;
    }
    if (lane == 63) wsum[wv] = v;
    __syncthreads();
    int wbase = 0;
    for (int j = 0; j < wv; ++j) wbase += wsum[j];
    int run = wbase + v - s;               // exclusive prefix for this thread's chunk
    for (int i = beg; i < end; ++i) {
        int val = cnt[i];
        rowptr[i] = run;
        run += val;
    }
    if (tid == 1023) rowptr[n] = run;
}

// ---------------- edge-compute + scatter, NO atomics (slots precomputed) ---------------------
// recH (2x uint4 = 32 B/edge):
//   [0]: pk(ae0,e1x) pk(e1y,e1z) col pk(q12,q22)    <- wave0's half
//   [1]: pk(q00,q01) pk(q02,q11) col 0              <- wave1's half
// slot = row[node] + loc[e]; all gathers are L2-resident (pos 240KB, row 80KB, tab 320KB).
__global__ void k_edge_fill(const float* pos, const float* alpha,
                            const int* ei, const float* tab, const int* z,
                            const int* row_dst, const int* row_src,
                            const int* loc_dst, const int* loc_src,
                            uint4* recH, int2* rec_src, int E) {
    int e = blockIdx.x * blockDim.x + threadIdx.x;
    if (e >= E) return;
    int sn = ei[e], dn = ei[E + e];
    float rx = pos[dn * 3]     - pos[sn * 3];
    float ry = pos[dn * 3 + 1] - pos[sn * 3 + 1];
    float rz = pos[dn * 3 + 2] - pos[sn * 3 + 2];
    float d = sqrtf(rx * rx + ry * ry + rz * rz + 1e-12f);
    float inv = 1.0f / d;
    rx *= inv; ry *= inv; rz *= inv;
    float u = fminf(d, RCUT) * ((float)(TTAB - 1) / RCUT);
    int i0 = (int)u; if (i0 > TTAB - 2) i0 = TTAB - 2;
    float f = u - (float)i0;
    const float* t0 = tab + i0 * 40;
    float c0 = t0[0] + f * (t0[40] - t0[0]);
    float c1 = t0[1] + f * (t0[41] - t0[1]);
    float c2 = t0[2] + f * (t0[42] - t0[2]);
    float al = alpha[e];
    float ae0 = san(al * c0);
    float k1 = 1.73205081f * al * c1;      // sqrt(3)*alpha*coeff1
    float k2 = al * c2;
    float e20 = san(5.47722558f * rx * ry * k2);                             // sqrt(30) xy
    float e21 = san(5.47722558f * ry * rz * k2);
    float e22 = san(1.58113883f * (2.f * rz * rz - rx * rx - ry * ry) * k2); // sqrt(2.5)
    float e23 = san(5.47722558f * rx * rz * k2);
    float e24 = san(2.73861279f * (rx * rx - ry * ry) * k2);                 // sqrt(7.5)
    const float S2 = 0.70710678f, S6 = 0.40824829f;
    float q00 = -S6 * e22 + S2 * e24;
    float q01 = S2 * e20;
    float q02 = S2 * e23;
    float q11 = -S6 * e22 - S2 * e24;
    float q12 = S2 * e21;
    float q22 = 2.f * S6 * e22;
    int p  = row_dst[dn] + loc_dst[e];
    int p2 = row_src[sn] + loc_src[e];
    uint4 r0, r1;
    r0.x = pk(ae0, san(k1 * rx));
    r0.y = pk(san(k1 * ry), san(k1 * rz));
    r0.z = (unsigned)sn;
    r0.w = pk(q12, q22);
    r1.x = pk(q00, q01);
    r1.y = pk(q02, q11);
    r1.z = (unsigned)sn;
    r1.w = 0u;
    recH[(size_t)p * 2]     = r0;
    recH[(size_t)p * 2 + 1] = r1;
    float uc = fminf(u, (float)(TTAB - 1) - 1e-3f);
    rec_src[p2] = make_int2(__float_as_int(uc), z[dn]);
}

// ---------------- aggr (src-sorted records) + initial node embed -----------------------------
// wave-synchronous: all LDS is per-wave
__global__ __launch_bounds__(256) void k_aggr(const int* row_src, const int2* recs,
        const int* z, const float* tab, const float* ne_emb, const float* atom_emb,
        const float* ne_cw, const float* ne_cb,
        float* sbuf, float* vbuf, int N) {
    __shared__ float part[4][64];
    __shared__ float cat[4][64];
    int wv = threadIdx.x >> 6, lane = threadIdx.x & 63;
    int n = blockIdx.x * 4 + wv;
    bool act = n < N;
    int g = lane >> 5, li = lane & 31;
    float acc = 0.f;
    if (act) {
        int r0 = row_src[n], r1 = row_src[n + 1];
        int half = (r1 - r0) >> 1;
        int kb = g ? (r0 + half) : r0;
        int ke = g ? r1 : (r0 + half);
        int k = kb;
        for (; k + 2 <= ke; k += 2) {
            int2 rA = recs[k], rB = recs[k + 1];
            float uA = __int_as_float(rA.x), uB = __int_as_float(rB.x);
            int iA = (int)uA, iB = (int)uB;
            float fA = uA - (float)iA, fB = uB - (float)iB;
            float wA0 = tab[iA * 40 + 4 + li], wA1 = tab[iA * 40 + 44 + li];
            float wB0 = tab[iB * 40 + 4 + li], wB1 = tab[iB * 40 + 44 + li];
            float eA = ne_emb[rA.y * 32 + li], eB = ne_emb[rB.y * 32 + li];
            acc += (wA0 + fA * (wA1 - wA0)) * eA + (wB0 + fB * (wB1 - wB0)) * eB;
        }
        for (; k < ke; ++k) {
            int2 r = recs[k];
            float u = __int_as_float(r.x);
            int i0 = (int)u; float f = u - (float)i0;
            float w0 = tab[i0 * 40 + 4 + li], w1 = tab[i0 * 40 + 44 + li];
            acc += (w0 + f * (w1 - w0)) * ne_emb[r.y * 32 + li];
        }
    }
    part[wv][lane] = acc;
    __builtin_amdgcn_wave_barrier();
    if (act && lane < 32) {
        cat[wv][lane] = atom_emb[z[n] * 32 + lane];
        cat[wv][32 + lane] = part[wv][lane] + part[wv][32 + lane];
    }
    __builtin_amdgcn_wave_barrier();
    if (act && lane < 32) {
        float so = ne_cb[lane];
        for (int j = 0; j < 64; ++j) so += cat[wv][j] * ne_cw[j * 32 + lane];
        sbuf[n * 32 + lane] = so;
    }
    if (act && lane < 48) vbuf[n * 48 + lane] = 0.f;
}

// half-block s accumulate (2 edges per lane-half)
#define SBLK2(BIDX, X0, X1)                                                             \
    {                                                                                   \
        int e_ = ((BIDX) << 2) + 2 * h;                                                 \
        float4 A0 = eA[e_], A1 = eA[e_ + 1];                                            \
        a0  += X0 * A0.x + X1 * A1.x;                                                   \
        a1x += X0 * A0.y + X1 * A1.y;                                                   \
        a1y += X0 * A0.z + X1 * A1.z;                                                   \
        a1z += X0 * A0.w + X1 * A1.w;                                                   \
    }

// one-edge v accumulate (edge slot g of block)
#define VBLK1(BIDX, U, V, W)                                                            \
    {                                                                                   \
        int e_ = ((BIDX) << 2) + g;                                                     \
        float4 Aa = eA[e_];                                                             \
        float4 Qa = eQ[e_];                                                             \
        float2 Ra = eR[e_];                                                             \
        adv += U * Aa.y + V * Aa.z + W * Aa.w;                                          \
        a2x += U * Aa.x; a2y += V * Aa.x; a2z += W * Aa.x;                              \
        a3x += Qa.x * U + Qa.y * V + Qa.z * W;                                          \
        a3y += Qa.y * U + Qa.w * V + Ra.x * W;                                          \
        a3z += Qa.z * U + Ra.x * V + Ra.y * W;                                          \
    }

// ---------------- fused layer: 1 node / 128-thread block, specialized waves ------------------
// wave0 = s-path (64 lanes: 32 dims x 2 edge-slots), wave1 = v-path (64 lanes: 16 dims x 4 slots).
// PROVEN OPTIMUM (round 8: 74us @ 36 VGPR / 4.6KB LDS / 66% occupancy). Lessons encoded:
//  - r6: transposed per-lane weight rows are wave-uncoalesced -> keep w[i*32+lane] column loads.
//  - r9: deeper pipelines / duplicated staging cost occupancy -> keep depth-2 + shared staging.
//  - r10: split-K + partial accumulators cost VGPR (36->56, occ 66->40%) -> keep single accums.
//  This kernel is latency-bound and lives off wave-level parallelism; do not trade occupancy.
__global__ __launch_bounds__(128) void k_layer(const int* __restrict__ row_dst,
        const uint4* __restrict__ recH,
        const float* __restrict__ sOld, const float* __restrict__ vOld,
        const float* w00, const float* w110, const float* w01,
        const float* w10, const float* w12,
        const float* self_ws, const float* self_wv,
        const float* pre_ws, const float* pre_wv,
        const float* post_ws, const float* post_wv,
        const float* ln_g, const float* ln_b,
        const float* g_w1, const float* g_b1,
        const float* g_w2, const float* g_b2,
        float* __restrict__ sNew, float* __restrict__ vNew,
        float* __restrict__ out, int N) {
    __shared__ __align__(16) float4 eA[64];
    __shared__ __align__(16) float4 eQ[64];
    __shared__ __align__(16) float2 eR[64];
    __shared__ __align__(16) int    eC[64];
    __shared__ float M[240];
    __shared__ float S[32], Vt[48], P[48];
    int wv = threadIdx.x >> 6, lane = threadIdx.x & 63;
    int n = blockIdx.x;
    int r0 = row_dst[n], r1 = row_dst[n + 1];
    int deg = r1 - r0;
    int cap = deg < 64 ? deg : 64;
    int nblk = cap >> 2;

    // ---- staging: wave0 -> eA,eR,eC + S ; wave1 -> eQ + Vt ----
    if (wv == 0) {
        if (lane < cap) {
            uint4 rA = recH[(size_t)(r0 + lane) * 2];
            float2 p0 = upk(rA.x), p1 = upk(rA.y), p3 = upk(rA.w);
            eA[lane] = make_float4(p0.x, p0.y, p1.x, p1.y);
            eR[lane] = make_float2(p3.x, p3.y);
            eC[lane] = (int)rA.z;
        }
        if (lane < 32) S[lane] = sOld[(size_t)n * 32 + lane];
    } else {
        if (lane < cap) {
            uint4 rB = recH[(size_t)(r0 + lane) * 2 + 1];
            float2 q0 = upk(rB.x), q1 = upk(rB.y);
            eQ[lane] = make_float4(q0.x, q0.y, q1.x, q1.y);
        }
        if (lane < 48) {
            int c_ = lane >> 4, o_ = lane & 15;
            Vt[c_ * 16 + o_] = vOld[(size_t)n * 48 + o_ * 3 + c_];
        }
    }
    __syncthreads();                                   // #1: staging complete

    const int4* eC4 = (const int4*)eC;
    if (wv == 0) {
        // ================= s-path wave =================
        int h = lane >> 5, d = lane & 31;
        float a0 = 0.f, a1x = 0.f, a1y = 0.f, a1z = 0.f;
        float xA0 = 0.f, xA1 = 0.f, xB0 = 0.f, xB1 = 0.f;
        if (nblk > 0) {
            int4 c4 = eC4[0];
            xA0 = sOld[(h ? c4.z : c4.x) * 32 + d];
            xA1 = sOld[(h ? c4.w : c4.y) * 32 + d];
        }
        if (nblk > 1) {
            int4 c4 = eC4[1];
            xB0 = sOld[(h ? c4.z : c4.x) * 32 + d];
            xB1 = sOld[(h ? c4.w : c4.y) * 32 + d];
        }
        int b = 0;
        for (; b + 2 <= nblk; b += 2) {
            int4 c40 = (b + 2 < nblk) ? eC4[b + 2] : make_int4(0, 0, 0, 0);
            int4 c41 = (b + 3 < nblk) ? eC4[b + 3] : make_int4(0, 0, 0, 0);
            float t0 = sOld[(h ? c40.z : c40.x) * 32 + d];
            float t1 = sOld[(h ? c40.w : c40.y) * 32 + d];
            float u0 = sOld[(h ? c41.z : c41.x) * 32 + d];
            float u1 = sOld[(h ? c41.w : c41.y) * 32 + d];
            SBLK2(b, xA0, xA1);
            SBLK2(b + 1, xB0, xB1);
            xA0 = t0; xA1 = t1; xB0 = u0; xB1 = u1;
        }
        if (b < nblk) { SBLK2(b, xA0, xA1); }
        for (int k = r0 + (nblk << 2); k < r1; ++k) {   // tail (+ deg>64 overflow), half 0 only
            if (h == 0) {
                uint4 rA = recH[(size_t)k * 2];
                float2 p0 = upk(rA.x), p1 = upk(rA.y);
                int cc = (int)rA.z;
                float xx = sOld[cc * 32 + d];
                a0 += xx * p0.x; a1x += xx * p0.y; a1y += xx * p1.x; a1z += xx * p1.y;
            }
        }
        a0  += __shfl_xor(a0, 32, 64);
        a1x += __shfl_xor(a1x, 32, 64);
        a1y += __shfl_xor(a1y, 32, 64);
        a1z += __shfl_xor(a1z, 32, 64);
        if (lane < 32) {
            M[lane] = a0; M[32 + lane] = a1x; M[64 + lane] = a1y; M[96 + lane] = a1z;
        }
    } else {
        // ================= v-path wave =================
        int g = lane >> 4, m = lane & 15;
        float adv = 0.f, a2x = 0.f, a2y = 0.f, a2z = 0.f, a3x = 0.f, a3y = 0.f, a3z = 0.f;
        float uA = 0.f, vA = 0.f, wA = 0.f, uB = 0.f, vB = 0.f, wB = 0.f;
        if (nblk > 0) {
            const float* vp = vOld + (size_t)eC[g] * 48 + m * 3;
            uA = vp[0]; vA = vp[1]; wA = vp[2];
        }
        if (nblk > 1) {
            const float* vp = vOld + (size_t)eC[4 + g] * 48 + m * 3;
            uB = vp[0]; vB = vp[1]; wB = vp[2];
        }
        int b = 0;
        for (; b + 2 <= nblk; b += 2) {
            int cn0 = (b + 2 < nblk) ? eC[(b + 2) * 4 + g] : 0;
            int cn1 = (b + 3 < nblk) ? eC[(b + 3) * 4 + g] : 0;
            const float* q0 = vOld + (size_t)cn0 * 48 + m * 3;
            const float* q1 = vOld + (size_t)cn1 * 48 + m * 3;
            float tu = q0[0], tv = q0[1], tw = q0[2];
            float su = q1[0], sv = q1[1], sw = q1[2];
            VBLK1(b, uA, vA, wA);
            VBLK1(b + 1, uB, vB, wB);
            uA = tu; vA = tv; wA = tw; uB = su; vB = sv; wB = sw;
        }
        if (b < nblk) { VBLK1(b, uA, vA, wA); }
        for (int k = r0 + (nblk << 2); k < r1; ++k) {   // tail, slot group 0 only
            if (g == 0) {
                uint4 rA = recH[(size_t)k * 2];
                uint4 rB = recH[(size_t)k * 2 + 1];
                float2 p0 = upk(rA.x), p1 = upk(rA.y), p3 = upk(rA.w);
                float2 q0 = upk(rB.x), q1 = upk(rB.y);
                int cc = (int)rA.z;
                const float* vp = vOld + (size_t)cc * 48 + m * 3;
                float vx = vp[0], vy = vp[1], vz = vp[2];
                adv += vx * p0.y + vy * p1.x + vz * p1.y;
                a2x += vx * p0.x; a2y += vy * p0.x; a2z += vz * p0.x;
                a3x += q0.x * vx + q0.y * vy + q1.x * vz;
                a3y += q0.y * vx + q1.y * vy + p3.x * vz;
                a3z += q1.x * vx + p3.x * vy + p3.y * vz;
            }
        }
        adv += __shfl_xor(adv, 16, 64); adv += __shfl_xor(adv, 32, 64);
        a2x += __shfl_xor(a2x, 16, 64); a2x += __shfl_xor(a2x, 32, 64);
        a2y += __shfl_xor(a2y, 16, 64); a2y += __shfl_xor(a2y, 32, 64);
        a2z += __shfl_xor(a2z, 16, 64); a2z += __shfl_xor(a2z, 32, 64);
        a3x += __shfl_xor(a3x, 16, 64); a3x += __shfl_xor(a3x, 32, 64);
        a3y += __shfl_xor(a3y, 16, 64); a3y += __shfl_xor(a3y, 32, 64);
        a3z += __shfl_xor(a3z, 16, 64); a3z += __shfl_xor(a3z, 32, 64);
        if (lane < 16) {
            M[128 + m] = adv;
            M[144 + m] = a2x; M[160 + m] = a2y; M[176 + m] = a2z;
            M[192 + m] = a3x; M[208 + m] = a3y; M[224 + m] = a3z;
        }
    }
    __syncthreads();                                   // #2: moments complete

    // ================= node update, split across the two waves =================
    float sln = 0.f, pv = 0.f;
    int c = lane >> 4, o = lane & 15;
    if (wv == 0) {
        // --- s-chain ---
        float s1 = 0.f;
        if (lane < 32) {
            for (int i = 0; i < 32; ++i) s1 += M[i] * w00[i * 32 + lane];
            for (int v = 0; v < 16; ++v) s1 += M[128 + v] * w110[v * 32 + lane];
            for (int i = 0; i < 32; ++i) s1 += S[i] * self_ws[i * 32 + lane];
        }
        __builtin_amdgcn_wave_barrier();
        if (lane < 32) S[lane] = s1;
        __builtin_amdgcn_wave_barrier();
        float ps = 0.f;
        if (lane < 48) {
            for (int i = 0; i < 32; ++i) ps += S[i] * pre_ws[i * 48 + lane];
            P[lane] = ps;                               // P[32:48) = gate pre-activation for wave1
        }
        __builtin_amdgcn_wave_barrier();
        float sc = (lane < 32) ? siluf(ps) : 0.f;
        if (lane < 32) S[lane] = sc;
        __builtin_amdgcn_wave_barrier();
        float s2 = 0.f;
        if (lane < 32) { for (int i = 0; i < 32; ++i) s2 += S[i] * post_ws[i * 32 + lane]; }
        float mu = s2;
        mu += __shfl_xor(mu, 1, 32); mu += __shfl_xor(mu, 2, 32);
        mu += __shfl_xor(mu, 4, 32); mu += __shfl_xor(mu, 8, 32); mu += __shfl_xor(mu, 16, 32);
        mu *= (1.0f / 32.0f);
        float t = s2 - mu;
        float var = t * t;
        var += __shfl_xor(var, 1, 32); var += __shfl_xor(var, 2, 32);
        var += __shfl_xor(var, 4, 32); var += __shfl_xor(var, 8, 32); var += __shfl_xor(var, 16, 32);
        var *= (1.0f / 32.0f);
        if (lane < 32) sln = t * rsqrtf(var + 1e-5f) * ln_g[lane] + ln_b[lane];
    } else {
        // --- v-chain (up to the gate dependency) ---
        float v1 = 0.f;
        if (lane < 48) {
            for (int i = 0; i < 32; ++i) v1 += M[32 + c * 32 + i] * w01[i * 16 + o];
            for (int v = 0; v < 16; ++v) v1 += M[144 + c * 16 + v] * w10[v * 16 + o];
            for (int v = 0; v < 16; ++v) v1 += M[192 + c * 16 + v] * w12[v * 16 + o];
            for (int v = 0; v < 16; ++v) v1 += Vt[c * 16 + v] * self_wv[v * 16 + o];
        }
        __builtin_amdgcn_wave_barrier();
        if (lane < 48) Vt[lane] = v1;
        __builtin_amdgcn_wave_barrier();
        if (lane < 48) {
            for (int v = 0; v < 16; ++v) pv += Vt[c * 16 + v] * pre_wv[v * 16 + o];
        }
    }
    __syncthreads();                                   // #3: P (gate) ready for wave1

    float v3 = 0.f;
    if (wv == 1) {
        float v2 = (lane < 48) ? pv * sigmoidf_(P[32 + o]) : 0.f;
        __builtin_amdgcn_wave_barrier();
        if (lane < 48) Vt[lane] = v2;
        __builtin_amdgcn_wave_barrier();
        if (lane < 48) { for (int v = 0; v < 16; ++v) v3 += Vt[c * 16 + v] * post_wv[v * 16 + o]; }
        __builtin_amdgcn_wave_barrier();
        if (lane < 48) Vt[lane] = v3;
        __builtin_amdgcn_wave_barrier();
        if (lane < 16) {
            float vx = Vt[lane], vy = Vt[16 + lane], vz = Vt[32 + lane];
            P[lane] = sqrtf(vx * vx + vy * vy + vz * vz + 1e-12f);
        }
        __builtin_amdgcn_wave_barrier();
        if (lane < 16) {
            float x = g_b1[lane];
            for (int mm = 0; mm < 16; ++mm) x += P[mm] * g_w1[mm * 16 + lane];
            P[16 + lane] = siluf(x);
        }
    }
    __syncthreads();                                   // #4: d1 ready for wave0

    if (wv == 0) {
        if (lane < 32) {
            float dl = g_b2[lane];
            for (int oo = 0; oo < 16; ++oo) dl += P[16 + oo] * g_w2[oo * 32 + lane];
            float sfin = sln + dl;
            if (out) out[(size_t)n * 80 + lane] = sfin;
            else     sNew[(size_t)n * 32 + lane] = sfin;
        }
    } else {
        if (lane < 48) {
            if (out) out[(size_t)n * 80 + 32 + o * 3 + c] = v3;
            else     vNew[(size_t)n * 48 + o * 3 + c] = v3;
        }
    }
}

extern "C" void kernel_launch(void* const* d_in, const int* in_sizes, int n_in,
                              void* d_out, int out_size, void* d_ws, size_t ws_size,
                              hipStream_t stream) {
    auto F = [&](int i) { return (const float*)d_in[i]; };
    const int* z  = (const int*)d_in[31];
    const int* ei = (const int*)d_in[32];
    int N = in_sizes[0] / 3;
    int E = in_sizes[1];

    char* w = (char*)d_ws;
    size_t off = 0;
    auto take = [&](size_t bytes) { size_t cur = off; off += (bytes + 255) & ~(size_t)255; return cur; };
    uint4* recH    = (uint4*)(w + take((size_t)E * 32));
    int2*  rec_src = (int2*)(w + take((size_t)E * 8));
    int*   loc_dst = (int*)(w + take((size_t)E * 4));
    int*   loc_src = (int*)(w + take((size_t)E * 4));
    float* tab     = (float*)(w + take((size_t)TTAB * 40 * 4));
    int* cnt_dst   = (int*)(w + take((size_t)2 * N * 4));
    int* cnt_src   = cnt_dst + N;
    int* row_dst   = (int*)(w + take((size_t)(N + 1) * 4));
    int* row_src   = (int*)(w + take((size_t)(N + 1) * 4));
    float* sA      = (float*)(w + take((size_t)N * 32 * 4));
    float* vA      = (float*)(w + take((size_t)N * 48 * 4));
    float* sB      = (float*)(w + take((size_t)N * 32 * 4));
    float* vB      = (float*)(w + take((size_t)N * 48 * 4));

    hipMemsetAsync(cnt_dst, 0, (size_t)2 * N * 4, stream);

    int nbc = (E + 255) / 256;
    k_tabcount<<<TTAB + nbc, 256, 0, stream>>>(F(8), F(9), F(10), F(11),
                                               F(12), F(13), F(4), F(5), tab,
                                               ei, cnt_dst, cnt_src, loc_dst, loc_src, E);
    k_scan2<<<2, 1024, 0, stream>>>(cnt_dst, row_dst, cnt_src, row_src, N);
    k_edge_fill<<<nbc, 256, 0, stream>>>(F(0), F(1), ei, tab, z,
                                         row_dst, row_src, loc_dst, loc_src,
                                         recH, rec_src, E);

    int nb = (N + 3) / 4;
    k_aggr<<<nb, 256, 0, stream>>>(row_src, rec_src, z, tab, F(3), F(2),
                                   F(6), F(7), sA, vA, N);

    float* sIn = sA; float* vIn = vA;
    float* sOut = sB; float* vOut = vB;
    for (int li = 0; li < 4; ++li) {
        float* outp = (li == 3) ? (float*)d_out : nullptr;
        k_layer<<<N, 128, 0, stream>>>(row_dst, recH,
                                        sIn, vIn,
                                        F(14) + li * 32 * 32, F(15) + li * 16 * 32,
                                        F(16) + li * 32 * 16, F(17) + li * 16 * 16,
                                        F(18) + li * 16 * 16,
                                        F(19) + li * 32 * 32, F(20) + li * 16 * 16,
                                        F(21) + li * 32 * 48, F(22) + li * 16 * 16,
                                        F(23) + li * 32 * 32, F(24) + li * 16 * 16,
                                        F(25) + li * 32, F(26) + li * 32,
                                        F(27) + li * 16 * 16, F(28) + li * 16,
                                        F(29) + li * 16 * 32, F(30) + li * 32,
                                        sOut, vOut, outp, N);
        float* ts = sIn; sIn = sOut; sOut = ts;
        float* tv = vIn; vIn = vOut; vOut = tv;
    }
}